// Round 6
// baseline (139.195 us; speedup 1.0000x reference)
//
#include <hip/hip_runtime.h>

typedef float f32x4 __attribute__((ext_vector_type(4)));
typedef float f32x2 __attribute__((ext_vector_type(2)));
typedef short bf16x8 __attribute__((ext_vector_type(8)));

#define N_TOT 8192
#define L_OBS 20
#define P_PRED 30
#define E_DIM 64
#define H_DIM 128
#define C_DIM 2048
#define G_DIM 512
#define M_ROWS 32
#define NTH 512
#define A_PAD 200   // bf16 elems per A row (400 B rows, 16B aligned)

#define K1 1.442695041f
#define K2 2.885390082f

static __device__ __forceinline__ unsigned short f2bf(float f) {
  union { float f; unsigned int u; } v; v.f = f;
  unsigned int u = v.u;
  return (unsigned short)((u + 0x7FFFu + ((u >> 16) & 1u)) >> 16);
}
// native transcendentals: avoid IEEE f32 div sequence without -ffast-math
static __device__ __forceinline__ float ex2(float x)  { float r; asm("v_exp_f32 %0, %1" : "=v"(r) : "v"(x)); return r; }
static __device__ __forceinline__ float rcpn(float x) { float r; asm("v_rcp_f32 %0, %1" : "=v"(r) : "v"(x)); return r; }
// HW round-to-nearest-even f32 pair -> packed bf16
static __device__ __forceinline__ unsigned int cvtpk(float lo, float hi) {
  unsigned int r; asm("v_cvt_pk_bf16_f32 %0, %1, %2" : "=v"(r) : "v"(lo), "v"(hi)); return r;
}
static __device__ __forceinline__ float bperm16(int u15, float v) {
  return __int_as_float(__builtin_amdgcn_ds_bpermute(u15 << 2, __float_as_int(v)));
}

__global__ __launch_bounds__(NTH, 2)
void lstm_traj(const float* __restrict__ img,      // [N][C]
               const float* __restrict__ obs_pos,  // [N][L][2]
               const float* __restrict__ obs_rel,  // [N][L][2]
               const int*   __restrict__ hist,     // [N]
               const float* __restrict__ h0,       // [H]
               const float* __restrict__ W_embed,  // [2][E]
               const float* __restrict__ b_embed,  // [E]
               const float* __restrict__ W_ih,     // [E][4H]
               const float* __restrict__ W_hh,     // [H][4H]
               const float* __restrict__ b_ih,     // [4H]
               const float* __restrict__ b_hh,     // [4H]
               const float* __restrict__ W_pred,   // [H+C][2]
               const float* __restrict__ b_pred,   // [2]
               float* __restrict__ out)            // [N][P][2]
{
  __shared__ unsigned short A_lds[2][M_ROWS][A_PAD]; // [e(64) | h(128) | pad]
  __shared__ float We_lds[2][E_DIM];
  __shared__ float be_lds[E_DIM];
  __shared__ float ip_lds[M_ROWS][2];

  const int t    = threadIdx.x;
  const int w    = t >> 6;        // wave 0..7
  const int l    = t & 63;
  const int u15  = l & 15;        // MFMA A-row / D-col index
  const int rq   = l >> 4;        // MFMA k-group / row-quad
  const int u    = w * 16 + u15;  // owned hidden unit 0..127
  const int wg0  = blockIdx.x * M_ROWS;
  const int grow = t >> 4;        // 0..31: row for obs-e/img work
  const int gj   = t & 15;        // 0..15: slot within row group

  const float* relrow = obs_rel + (wg0 + grow) * (L_OBS * 2);

  // ---- stage small weights to LDS ----
  if (t < 128) We_lds[t >> 6][t & 63] = W_embed[t];
  if (t < 64)  be_lds[t] = b_embed[t];
  __syncthreads();

  // ---- B fragments (gate weights) in registers: 24 frags = 96 VGPR ----
  bf16x8 B[4][6];
#pragma unroll
  for (int ks = 0; ks < 6; ++ks)
#pragma unroll
    for (int i = 0; i < 8; ++i) {
      const int k = ks * 32 + rq * 8 + i;
      const float* Wrow = (k < E_DIM) ? (W_ih + k * G_DIM) : (W_hh + (k - E_DIM) * G_DIM);
#pragma unroll
      for (int gt = 0; gt < 4; ++gt)
        B[gt][ks][i] = (short)f2bf(Wrow[gt * 128 + u]);
    }

  // ---- Wp^T fragments for rel-MFMA: rows 0..1 = pred comps, rest zero ----
  bf16x8 wpf[4];
#pragma unroll
  for (int ks4 = 0; ks4 < 4; ++ks4)
#pragma unroll
    for (int i = 0; i < 8; ++i) {
      const int k = ks4 * 32 + rq * 8 + i;  // h-part row of W_pred
      wpf[ks4][i] = (u15 < 2) ? (short)f2bf(W_pred[k * 2 + u15]) : (short)0;
    }

  // log2e-scaled negative biases (fold the exp2 scale into one fma per gate)
  const float nbi = -K1 * (b_ih[u]       + b_hh[u]);
  const float nbf = -K1 * (b_ih[128 + u] + b_hh[128 + u]);
  const float nbg = -K2 * (b_ih[256 + u] + b_hh[256 + u]);
  const float nbo = -K1 * (b_ih[384 + u] + b_hh[384 + u]);

  // ---- per-lane recurrent state: rows rt*16 + rq*4 + q, unit u ----
  const float h0u = h0[u];
  const unsigned short h0b = f2bf(h0u);
  float hf[2][4];
  float cs[2][4];
  int sact[2];
#pragma unroll
  for (int rt = 0; rt < 2; ++rt) {
    sact[rt] = 0;
#pragma unroll
    for (int q = 0; q < 4; ++q) {
      const int row = rt * 16 + rq * 4 + q;
      hf[rt][q] = h0u; cs[rt][q] = h0u;
      sact[rt] |= ((20 - hist[wg0 + row]) & 255) << (8 * q);
      A_lds[0][row][64 + u] = h0b;
    }
  }

  // ---- e for obs step 1 (uses obs_rel[:,2,:]) ----
  {
    const f32x2 rr = *(const f32x2*)(relrow + 2 * 2);
    const int j = gj * 4;
    const float e0 = fmaxf(fmaf(rr.x, We_lds[0][j],     fmaf(rr.y, We_lds[1][j],     be_lds[j])),     0.f);
    const float e1 = fmaxf(fmaf(rr.x, We_lds[0][j + 1], fmaf(rr.y, We_lds[1][j + 1], be_lds[j + 1])), 0.f);
    const float e2 = fmaxf(fmaf(rr.x, We_lds[0][j + 2], fmaf(rr.y, We_lds[1][j + 2], be_lds[j + 2])), 0.f);
    const float e3 = fmaxf(fmaf(rr.x, We_lds[0][j + 3], fmaf(rr.y, We_lds[1][j + 3], be_lds[j + 3])), 0.f);
    uint2 pk; pk.x = cvtpk(e0, e1); pk.y = cvtpk(e2, e3);
    *(uint2*)&A_lds[0][grow][j] = pk;
  }

  // ---- img_proj (16 lanes per row, coalesced float4) -> ip_lds ----
  {
    float ig0 = 0.f, ig1 = 0.f;
    const float* irow = img + (long)(wg0 + grow) * C_DIM;
#pragma unroll 4
    for (int i = 0; i < 32; ++i) {
      const int k0 = i * 64 + gj * 4;
      const f32x4 v  = *(const f32x4*)(irow + k0);
      const f32x4 wa = *(const f32x4*)(W_pred + (H_DIM + k0) * 2);
      const f32x4 wb = *(const f32x4*)(W_pred + (H_DIM + k0) * 2 + 4);
      ig0 = fmaf(v.x, wa.x, fmaf(v.y, wa.z, fmaf(v.z, wb.x, fmaf(v.w, wb.z, ig0))));
      ig1 = fmaf(v.x, wa.y, fmaf(v.y, wa.w, fmaf(v.z, wb.y, fmaf(v.w, wb.w, ig1))));
    }
#pragma unroll
    for (int m = 8; m >= 1; m >>= 1) { ig0 += __shfl_xor(ig0, m); ig1 += __shfl_xor(ig1, m); }
    if (gj == 0) { ip_lds[grow][0] = ig0 + b_pred[0]; ip_lds[grow][1] = ig1 + b_pred[1]; }
  }
  __syncthreads();  // A_lds[0], ip_lds visible

  // per-lane img_proj & pos for owned rows u15 (rt0) and 16+u15 (rt1)
  const float ipA0 = ip_lds[u15][0],      ipA1 = ip_lds[u15][1];
  const float ipB0 = ip_lds[16 + u15][0], ipB1 = ip_lds[16 + u15][1];
  float posA0 = obs_pos[(wg0 + u15) * (L_OBS * 2) + (L_OBS - 1) * 2];
  float posA1 = obs_pos[(wg0 + u15) * (L_OBS * 2) + (L_OBS - 1) * 2 + 1];
  float posB0 = obs_pos[(wg0 + 16 + u15) * (L_OBS * 2) + (L_OBS - 1) * 2];
  float posB1 = obs_pos[(wg0 + 16 + u15) * (L_OBS * 2) + (L_OBS - 1) * 2 + 1];

  int cur = 0;

  // gate nonlinearity + h-write: 5 ex2 + 2 rcp per output (merged tanh*sigmoid)
  auto gates_and_h = [&](f32x4 (&acc)[2][4], int nxt_, int s_, bool domask) {
#pragma unroll
    for (int rt = 0; rt < 2; ++rt) {
#pragma unroll
      for (int q = 0; q < 4; ++q) {
        const float A_ = ex2(fmaf(acc[rt][0][q], -K1, nbi));
        const float F_ = ex2(fmaf(acc[rt][1][q], -K1, nbf));
        const float B_ = ex2(fmaf(acc[rt][2][q], -K2, nbg));
        const float C_ = ex2(fmaf(acc[rt][3][q], -K1, nbo));
        const float P2 = 1.f + B_;
        const float PB = (1.f + A_) * P2;
        const float Q  = 1.f + F_;
        const float cn = fmaf(cs[rt][q], PB, (2.f - P2) * Q) * rcpn(PB * Q);
        const float cc = fmaxf(fminf(cn, 40.f), -40.f);   // tanh saturates; keeps (1-D_) finite
        const float D_ = ex2(-K2 * cc);
        const float hn = (1.f - D_) * rcpn((1.f + D_) * (1.f + C_)); // tanh(cn)*sigmoid(o)
        bool act = true;
        if (domask) act = s_ >= ((sact[rt] >> (8 * q)) & 255);
        if (act) { cs[rt][q] = cn; hf[rt][q] = hn; }
      }
      const unsigned int p01 = cvtpk(hf[rt][0], hf[rt][1]);
      const unsigned int p23 = cvtpk(hf[rt][2], hf[rt][3]);
      const int rowb = rt * 16 + rq * 4;
      A_lds[nxt_][rowb + 0][64 + u] = (unsigned short)p01;
      A_lds[nxt_][rowb + 1][64 + u] = (unsigned short)(p01 >> 16);
      A_lds[nxt_][rowb + 2][64 + u] = (unsigned short)p23;
      A_lds[nxt_][rowb + 3][64 + u] = (unsigned short)(p23 >> 16);
    }
  };

  // ================= obs phase: steps 1..18 (step 0 provably inactive) =================
#pragma unroll 1
  for (int s = 1; s < L_OBS - 1; ++s) {
    const int nxt = cur ^ 1;
    const int sN = (s + 2 <= L_OBS - 1) ? (s + 2) : (L_OBS - 1);  // branchless prefetch idx
    const f32x2 rrN = *(const f32x2*)(relrow + sN * 2);

    f32x4 acc[2][4];
#pragma unroll
    for (int rt = 0; rt < 2; ++rt)
#pragma unroll
      for (int gt = 0; gt < 4; ++gt) { acc[rt][gt].x = 0.f; acc[rt][gt].y = 0.f; acc[rt][gt].z = 0.f; acc[rt][gt].w = 0.f; }
#pragma unroll
    for (int ks = 0; ks < 6; ++ks)
#pragma unroll
      for (int rt = 0; rt < 2; ++rt) {
        const bf16x8 a = *(const bf16x8*)&A_lds[cur][rt * 16 + u15][ks * 32 + rq * 8];
#pragma unroll
        for (int gt = 0; gt < 4; ++gt)
          acc[rt][gt] = __builtin_amdgcn_mfma_f32_16x16x32_bf16(a, B[gt][ks], acc[rt][gt], 0, 0, 0);
      }

    // next-step e into A[nxt] (overlaps MFMA; garbage on last iter, never read in pred)
    {
      const int j = gj * 4;
      const float e0 = fmaxf(fmaf(rrN.x, We_lds[0][j],     fmaf(rrN.y, We_lds[1][j],     be_lds[j])),     0.f);
      const float e1 = fmaxf(fmaf(rrN.x, We_lds[0][j + 1], fmaf(rrN.y, We_lds[1][j + 1], be_lds[j + 1])), 0.f);
      const float e2 = fmaxf(fmaf(rrN.x, We_lds[0][j + 2], fmaf(rrN.y, We_lds[1][j + 2], be_lds[j + 2])), 0.f);
      const float e3 = fmaxf(fmaf(rrN.x, We_lds[0][j + 3], fmaf(rrN.y, We_lds[1][j + 3], be_lds[j + 3])), 0.f);
      uint2 pk; pk.x = cvtpk(e0, e1); pk.y = cvtpk(e2, e3);
      *(uint2*)&A_lds[nxt][grow][j] = pk;
    }

    gates_and_h(acc, nxt, s, true);
    cur = nxt;
    __syncthreads();
  }

  // ================= pred phase: 30 steps, ONE barrier per step =================
#pragma unroll 1
  for (int p = 0; p < P_PRED; ++p) {
    const bool last = (p == P_PRED - 1);

    f32x4 acc[2][4];
    f32x4 racc[2];
#pragma unroll
    for (int rt = 0; rt < 2; ++rt) {
      racc[rt].x = 0.f; racc[rt].y = 0.f; racc[rt].z = 0.f; racc[rt].w = 0.f;
#pragma unroll
      for (int gt = 0; gt < 4; ++gt) { acc[rt][gt].x = 0.f; acc[rt][gt].y = 0.f; acc[rt][gt].z = 0.f; acc[rt][gt].w = 0.f; }
    }

    // transient A-fragment: feeds rel-MFMA and gate h-MFMAs, then dies
#pragma unroll
    for (int ks4 = 0; ks4 < 4; ++ks4)
#pragma unroll
      for (int rt = 0; rt < 2; ++rt) {
        const bf16x8 a = *(const bf16x8*)&A_lds[cur][rt * 16 + u15][64 + ks4 * 32 + rq * 8];
        racc[rt] = __builtin_amdgcn_mfma_f32_16x16x32_bf16(wpf[ks4], a, racc[rt], 0, 0, 0);
        if (!last) {
#pragma unroll
          for (int gt = 0; gt < 4; ++gt)
            acc[rt][gt] = __builtin_amdgcn_mfma_f32_16x16x32_bf16(a, B[gt][ks4 + 2], acc[rt][gt], 0, 0, 0);
        }
      }

    // broadcast rel to all lanes for owned batch rows
    const float relA0 = bperm16(u15, racc[0].x) + ipA0;
    const float relA1 = bperm16(u15, racc[0].y) + ipA1;
    const float relB0 = bperm16(u15, racc[1].x) + ipB0;
    const float relB1 = bperm16(u15, racc[1].y) + ipB1;
    posA0 += relA0; posA1 += relA1;
    posB0 += relB0; posB1 += relB1;
    if (rq == 0) {
      float2 oA; oA.x = posA0; oA.y = posA1;
      float2 oB; oB.x = posB0; oB.y = posB1;
      *(float2*)&out[((long)(wg0 + u15) * P_PRED + p) * 2]      = oA;
      *(float2*)&out[((long)(wg0 + 16 + u15) * P_PRED + p) * 2] = oB;
    }
    if (last) break;

    // e fragments JIT per (rt,kb): built and immediately consumed by the MFMA
#pragma unroll
    for (int rt = 0; rt < 2; ++rt) {
      const float r0 = rt ? relB0 : relA0;
      const float r1 = rt ? relB1 : relA1;
#pragma unroll
      for (int kb = 0; kb < 2; ++kb) {
        union { unsigned int uu[4]; bf16x8 v; } pk;
#pragma unroll
        for (int ii = 0; ii < 4; ++ii) {
          const int k0 = kb * 32 + rq * 8 + 2 * ii;
          const float ea = fmaxf(fmaf(r0, We_lds[0][k0],     fmaf(r1, We_lds[1][k0],     be_lds[k0])),     0.f);
          const float eb = fmaxf(fmaf(r0, We_lds[0][k0 + 1], fmaf(r1, We_lds[1][k0 + 1], be_lds[k0 + 1])), 0.f);
          pk.uu[ii] = cvtpk(ea, eb);
        }
#pragma unroll
        for (int gt = 0; gt < 4; ++gt)
          acc[rt][gt] = __builtin_amdgcn_mfma_f32_16x16x32_bf16(pk.v, B[gt][kb], acc[rt][gt], 0, 0, 0);
      }
    }

    const int nxt = cur ^ 1;
    gates_and_h(acc, nxt, 0, false);
    cur = nxt;
    __syncthreads();
  }
}

extern "C" void kernel_launch(void* const* d_in, const int* in_sizes, int n_in,
                              void* d_out, int out_size, void* d_ws, size_t ws_size,
                              hipStream_t stream) {
  (void)in_sizes; (void)n_in; (void)out_size; (void)d_ws; (void)ws_size;
  lstm_traj<<<dim3(N_TOT / M_ROWS), dim3(NTH), 0, stream>>>(
      (const float*)d_in[0],  // img_embedding
      (const float*)d_in[1],  // obs_pos
      (const float*)d_in[2],  // obs_pos_rel
      (const int*)  d_in[3],  // obs_hist_size
      (const float*)d_in[4],  // h0
      (const float*)d_in[5],  // W_embed
      (const float*)d_in[6],  // b_embed
      (const float*)d_in[7],  // W_ih
      (const float*)d_in[8],  // W_hh
      (const float*)d_in[9],  // b_ih
      (const float*)d_in[10], // b_hh
      (const float*)d_in[11], // W_pred
      (const float*)d_in[12], // b_pred
      (float*)d_out);
}

// Round 7
// 127.727 us; speedup vs baseline: 1.0898x; 1.0898x over previous
//
#include <hip/hip_runtime.h>

typedef float f32x4 __attribute__((ext_vector_type(4)));
typedef float f32x2 __attribute__((ext_vector_type(2)));
typedef short bf16x8 __attribute__((ext_vector_type(8)));

#define N_TOT 8192
#define L_OBS 20
#define P_PRED 30
#define E_DIM 64
#define H_DIM 128
#define C_DIM 2048
#define G_DIM 512
#define M_ROWS 32
#define NTH 512
#define A_PAD 200   // bf16 elems per A row (400 B rows, 16B aligned)

#define K1 1.442695041f
#define K2 2.885390082f

static __device__ __forceinline__ unsigned short f2bf(float f) {
  union { float f; unsigned int u; } v; v.f = f;
  unsigned int u = v.u;
  return (unsigned short)((u + 0x7FFFu + ((u >> 16) & 1u)) >> 16);
}
static __device__ __forceinline__ float bf2f(unsigned short b) {
  union { unsigned int u; float f; } v; v.u = ((unsigned int)b) << 16;
  return v.f;
}
// native transcendentals: avoid IEEE f32 div sequence without -ffast-math
static __device__ __forceinline__ float ex2(float x)  { float r; asm("v_exp_f32 %0, %1" : "=v"(r) : "v"(x)); return r; }
static __device__ __forceinline__ float rcpn(float x) { float r; asm("v_rcp_f32 %0, %1" : "=v"(r) : "v"(x)); return r; }
// HW round-to-nearest-even f32 pair -> packed bf16
static __device__ __forceinline__ unsigned int cvtpk(float lo, float hi) {
  unsigned int r; asm("v_cvt_pk_bf16_f32 %0, %1, %2" : "=v"(r) : "v"(lo), "v"(hi)); return r;
}

__global__ __launch_bounds__(NTH, 2)
void lstm_traj(const float* __restrict__ img,      // [N][C]
               const float* __restrict__ obs_pos,  // [N][L][2]
               const float* __restrict__ obs_rel,  // [N][L][2]
               const int*   __restrict__ hist,     // [N]
               const float* __restrict__ h0,       // [H]
               const float* __restrict__ W_embed,  // [2][E]
               const float* __restrict__ b_embed,  // [E]
               const float* __restrict__ W_ih,     // [E][4H]
               const float* __restrict__ W_hh,     // [H][4H]
               const float* __restrict__ b_ih,     // [4H]
               const float* __restrict__ b_hh,     // [4H]
               const float* __restrict__ W_pred,   // [H+C][2]
               const float* __restrict__ b_pred,   // [2]
               float* __restrict__ out)            // [N][P][2]
{
  __shared__ unsigned short A_lds[2][M_ROWS][A_PAD]; // [e(64) | h(128) | pad]
  __shared__ float We_lds[2][E_DIM];
  __shared__ float be_lds[E_DIM];
  __shared__ float Wp_lds[H_DIM][2];

  const int t    = threadIdx.x;
  const int w    = t >> 6;        // wave 0..7
  const int l    = t & 63;
  const int u15  = l & 15;        // MFMA A-row / D-col index
  const int rq   = l >> 4;        // MFMA k-group / row-quad
  const int u    = w * 16 + u15;  // owned hidden unit 0..127
  const int wg0  = blockIdx.x * M_ROWS;
  const int grow = t >> 4;        // 0..31: row for e/rel/img work
  const int gj   = t & 15;        // 0..15: slot within row group

  const float* relrow = obs_rel + (wg0 + grow) * (L_OBS * 2);

  // ---- stage small weights to LDS ----
  if (t < 128) We_lds[t >> 6][t & 63] = W_embed[t];
  if (t < 64)  be_lds[t] = b_embed[t];
  if (t >= 128 && t < 384) ((float*)Wp_lds)[t - 128] = W_pred[t - 128];
  __syncthreads();

  // ---- B fragments (gate weights) in registers: 24 frags = 96 VGPR ----
  bf16x8 B[4][6];
#pragma unroll
  for (int ks = 0; ks < 6; ++ks)
#pragma unroll
    for (int i = 0; i < 8; ++i) {
      const int k = ks * 32 + rq * 8 + i;
      const float* Wrow = (k < E_DIM) ? (W_ih + k * G_DIM) : (W_hh + (k - E_DIM) * G_DIM);
#pragma unroll
      for (int gt = 0; gt < 4; ++gt)
        B[gt][ks][i] = (short)f2bf(Wrow[gt * 128 + u]);
    }

  // ---- bias vectors: acc chains are SEEDED with these (kills zero-init movs) ----
  f32x4 bias4[4];
#pragma unroll
  for (int gt = 0; gt < 4; ++gt) {
    const float b = b_ih[gt * 128 + u] + b_hh[gt * 128 + u];
    bias4[gt].x = b; bias4[gt].y = b; bias4[gt].z = b; bias4[gt].w = b;
  }

  // ---- per-lane recurrent state: rows rt*16 + rq*4 + q, unit u ----
  const float h0u = h0[u];
  const unsigned short h0b = f2bf(h0u);
  float hf[2][4];
  float cs[2][4];
  int sact[2];
#pragma unroll
  for (int rt = 0; rt < 2; ++rt) {
    sact[rt] = 0;
#pragma unroll
    for (int q = 0; q < 4; ++q) {
      const int row = rt * 16 + rq * 4 + q;
      hf[rt][q] = h0u; cs[rt][q] = h0u;
      sact[rt] |= ((20 - hist[wg0 + row]) & 255) << (8 * q);
      A_lds[0][row][64 + u] = h0b;
    }
  }

  // ---- e for obs step 1 (uses obs_rel[:,2,:]) ----
  {
    const f32x2 rr = *(const f32x2*)(relrow + 2 * 2);
    const int j = gj * 4;
    const float e0 = fmaxf(fmaf(rr.x, We_lds[0][j],     fmaf(rr.y, We_lds[1][j],     be_lds[j])),     0.f);
    const float e1 = fmaxf(fmaf(rr.x, We_lds[0][j + 1], fmaf(rr.y, We_lds[1][j + 1], be_lds[j + 1])), 0.f);
    const float e2 = fmaxf(fmaf(rr.x, We_lds[0][j + 2], fmaf(rr.y, We_lds[1][j + 2], be_lds[j + 2])), 0.f);
    const float e3 = fmaxf(fmaf(rr.x, We_lds[0][j + 3], fmaf(rr.y, We_lds[1][j + 3], be_lds[j + 3])), 0.f);
    uint2 pk; pk.x = cvtpk(e0, e1); pk.y = cvtpk(e2, e3);
    *(uint2*)&A_lds[0][grow][j] = pk;
  }

  // ---- pos init + img_proj (16 lanes per row, coalesced float4) ----
  float pos0 = obs_pos[(wg0 + grow) * (L_OBS * 2) + (L_OBS - 1) * 2];
  float pos1 = obs_pos[(wg0 + grow) * (L_OBS * 2) + (L_OBS - 1) * 2 + 1];
  float ip0 = 0.f, ip1 = 0.f;
  {
    const float* irow = img + (long)(wg0 + grow) * C_DIM;
#pragma unroll 4
    for (int i = 0; i < 32; ++i) {
      const int k0 = i * 64 + gj * 4;
      const f32x4 v  = *(const f32x4*)(irow + k0);
      const f32x4 wa = *(const f32x4*)(W_pred + (H_DIM + k0) * 2);
      const f32x4 wb = *(const f32x4*)(W_pred + (H_DIM + k0) * 2 + 4);
      ip0 = fmaf(v.x, wa.x, fmaf(v.y, wa.z, fmaf(v.z, wb.x, fmaf(v.w, wb.z, ip0))));
      ip1 = fmaf(v.x, wa.y, fmaf(v.y, wa.w, fmaf(v.z, wb.y, fmaf(v.w, wb.w, ip1))));
    }
#pragma unroll
    for (int m = 8; m >= 1; m >>= 1) { ip0 += __shfl_xor(ip0, m); ip1 += __shfl_xor(ip1, m); }
    ip0 += b_pred[0]; ip1 += b_pred[1];
  }
  __syncthreads();

  int cur = 0;

  // gate nonlinearity + h-write for ONE rt: 5 ex2 + 2 rcp per output.
  // acc already CONTAINS the bias (seeded via MFMA C operand).
  auto gates_rt = [&](f32x4 (&a4)[4], int rt, int nxt_, int s_, bool domask) {
#pragma unroll
    for (int q = 0; q < 4; ++q) {
      const float A_ = ex2(-K1 * a4[0][q]);
      const float F_ = ex2(-K1 * a4[1][q]);
      const float B_ = ex2(-K2 * a4[2][q]);
      const float C_ = ex2(-K1 * a4[3][q]);
      const float P2 = 1.f + B_;
      const float PB = (1.f + A_) * P2;
      const float Q  = 1.f + F_;
      const float cn = fmaf(cs[rt][q], PB, (2.f - P2) * Q) * rcpn(PB * Q);
      const float cc = fmaxf(fminf(cn, 40.f), -40.f);
      const float D_ = ex2(-K2 * cc);
      const float hn = (1.f - D_) * rcpn((1.f + D_) * (1.f + C_)); // tanh(cn)*sigmoid(o)
      bool act = true;
      if (domask) act = s_ >= ((sact[rt] >> (8 * q)) & 255);
      if (act) { cs[rt][q] = cn; hf[rt][q] = hn; }
    }
    const unsigned int p01 = cvtpk(hf[rt][0], hf[rt][1]);
    const unsigned int p23 = cvtpk(hf[rt][2], hf[rt][3]);
    const int rowb = rt * 16 + rq * 4;
    A_lds[nxt_][rowb + 0][64 + u] = (unsigned short)p01;
    A_lds[nxt_][rowb + 1][64 + u] = (unsigned short)(p01 >> 16);
    A_lds[nxt_][rowb + 2][64 + u] = (unsigned short)p23;
    A_lds[nxt_][rowb + 3][64 + u] = (unsigned short)(p23 >> 16);
  };

  // ================= obs phase: steps 1..18 (step 0 provably inactive) =================
#pragma unroll 1
  for (int s = 1; s < L_OBS - 1; ++s) {
    const int nxt = cur ^ 1;
    const int sN = (s + 2 <= L_OBS - 1) ? (s + 2) : (L_OBS - 1);  // branchless prefetch idx
    const f32x2 rrN = *(const f32x2*)(relrow + sN * 2);

    // rt-major MFMA: rt0's acc completes first -> its gates overlap rt1's MFMAs
    f32x4 acc[2][4];
#pragma unroll
    for (int rt = 0; rt < 2; ++rt) {
      {
        const bf16x8 a = *(const bf16x8*)&A_lds[cur][rt * 16 + u15][rq * 8];
#pragma unroll
        for (int gt = 0; gt < 4; ++gt)
          acc[rt][gt] = __builtin_amdgcn_mfma_f32_16x16x32_bf16(a, B[gt][0], bias4[gt], 0, 0, 0);
      }
#pragma unroll
      for (int ks = 1; ks < 6; ++ks) {
        const bf16x8 a = *(const bf16x8*)&A_lds[cur][rt * 16 + u15][ks * 32 + rq * 8];
#pragma unroll
        for (int gt = 0; gt < 4; ++gt)
          acc[rt][gt] = __builtin_amdgcn_mfma_f32_16x16x32_bf16(a, B[gt][ks], acc[rt][gt], 0, 0, 0);
      }
    }

    // next-step e into A[nxt] (independent; fills MFMA shadow)
    {
      const int j = gj * 4;
      const float e0 = fmaxf(fmaf(rrN.x, We_lds[0][j],     fmaf(rrN.y, We_lds[1][j],     be_lds[j])),     0.f);
      const float e1 = fmaxf(fmaf(rrN.x, We_lds[0][j + 1], fmaf(rrN.y, We_lds[1][j + 1], be_lds[j + 1])), 0.f);
      const float e2 = fmaxf(fmaf(rrN.x, We_lds[0][j + 2], fmaf(rrN.y, We_lds[1][j + 2], be_lds[j + 2])), 0.f);
      const float e3 = fmaxf(fmaf(rrN.x, We_lds[0][j + 3], fmaf(rrN.y, We_lds[1][j + 3], be_lds[j + 3])), 0.f);
      uint2 pk; pk.x = cvtpk(e0, e1); pk.y = cvtpk(e2, e3);
      *(uint2*)&A_lds[nxt][grow][j] = pk;
    }

    gates_rt(acc[0], 0, nxt, s, true);   // overlaps rt1 MFMA tail
    gates_rt(acc[1], 1, nxt, s, true);
    cur = nxt;
    __syncthreads();
  }

  // ================= pred phase: 30 steps (r4 two-barrier structure) =================
#pragma unroll 1
  for (int p = 0; p < P_PRED; ++p) {
    const bool last = (p == P_PRED - 1);

    // start the serial rel chain early: hv read + partial dot
    const bf16x8 hv = *(const bf16x8*)&A_lds[cur][grow][64 + gj * 8];
    float s0 = 0.f, s1 = 0.f;
#pragma unroll
    for (int i = 0; i < 8; ++i) {
      const float hfv = bf2f((unsigned short)hv[i]);
      s0 = fmaf(hfv, Wp_lds[gj * 8 + i][0], s0);
      s1 = fmaf(hfv, Wp_lds[gj * 8 + i][1], s1);
    }

    // h-part MFMAs (ks 2..5), rt-major, bias-seeded; overlaps the shuffle tree below
    f32x4 acc[2][4];
    if (!last) {
#pragma unroll
      for (int rt = 0; rt < 2; ++rt) {
        {
          const bf16x8 a = *(const bf16x8*)&A_lds[cur][rt * 16 + u15][64 + rq * 8];
#pragma unroll
          for (int gt = 0; gt < 4; ++gt)
            acc[rt][gt] = __builtin_amdgcn_mfma_f32_16x16x32_bf16(a, B[gt][2], bias4[gt], 0, 0, 0);
        }
#pragma unroll
        for (int ks4 = 1; ks4 < 4; ++ks4) {
          const bf16x8 a = *(const bf16x8*)&A_lds[cur][rt * 16 + u15][64 + ks4 * 32 + rq * 8];
#pragma unroll
          for (int gt = 0; gt < 4; ++gt)
            acc[rt][gt] = __builtin_amdgcn_mfma_f32_16x16x32_bf16(a, B[gt][ks4 + 2], acc[rt][gt], 0, 0, 0);
        }
      }
    }

    // finish rel reduction (serial shuffle tree, hidden under MFMAs)
#pragma unroll
    for (int m = 8; m >= 1; m >>= 1) { s0 += __shfl_xor(s0, m); s1 += __shfl_xor(s1, m); }
    const float rel0 = s0 + ip0, rel1 = s1 + ip1;
    pos0 += rel0; pos1 += rel1;
    if (gj == 0) {
      float2 o; o.x = pos0; o.y = pos1;
      *(float2*)&out[((long)(wg0 + grow) * P_PRED + p) * 2] = o;
    }
    if (last) break;

    // e = relu(rel @ W_embed + b_embed) into A[cur] cols 0..63
    {
      const int j = gj * 4;
      const float e0 = fmaxf(fmaf(rel0, We_lds[0][j],     fmaf(rel1, We_lds[1][j],     be_lds[j])),     0.f);
      const float e1 = fmaxf(fmaf(rel0, We_lds[0][j + 1], fmaf(rel1, We_lds[1][j + 1], be_lds[j + 1])), 0.f);
      const float e2 = fmaxf(fmaf(rel0, We_lds[0][j + 2], fmaf(rel1, We_lds[1][j + 2], be_lds[j + 2])), 0.f);
      const float e3 = fmaxf(fmaf(rel0, We_lds[0][j + 3], fmaf(rel1, We_lds[1][j + 3], be_lds[j + 3])), 0.f);
      uint2 pk; pk.x = cvtpk(e0, e1); pk.y = cvtpk(e2, e3);
      *(uint2*)&A_lds[cur][grow][j] = pk;
    }
    __syncthreads();  // barrier B: e visible

    // e-part MFMAs (ks 0..1), rt-major -> gates(rt0) overlaps rt1's e-MFMAs
#pragma unroll
    for (int rt = 0; rt < 2; ++rt)
#pragma unroll
      for (int ks = 0; ks < 2; ++ks) {
        const bf16x8 a = *(const bf16x8*)&A_lds[cur][rt * 16 + u15][ks * 32 + rq * 8];
#pragma unroll
        for (int gt = 0; gt < 4; ++gt)
          acc[rt][gt] = __builtin_amdgcn_mfma_f32_16x16x32_bf16(a, B[gt][ks], acc[rt][gt], 0, 0, 0);
      }

    const int nxt = cur ^ 1;
    gates_rt(acc[0], 0, nxt, 0, false);
    gates_rt(acc[1], 1, nxt, 0, false);
    cur = nxt;
    __syncthreads();  // barrier A: h visible
  }
}

extern "C" void kernel_launch(void* const* d_in, const int* in_sizes, int n_in,
                              void* d_out, int out_size, void* d_ws, size_t ws_size,
                              hipStream_t stream) {
  (void)in_sizes; (void)n_in; (void)out_size; (void)d_ws; (void)ws_size;
  lstm_traj<<<dim3(N_TOT / M_ROWS), dim3(NTH), 0, stream>>>(
      (const float*)d_in[0],  // img_embedding
      (const float*)d_in[1],  // obs_pos
      (const float*)d_in[2],  // obs_pos_rel
      (const int*)  d_in[3],  // obs_hist_size
      (const float*)d_in[4],  // h0
      (const float*)d_in[5],  // W_embed
      (const float*)d_in[6],  // b_embed
      (const float*)d_in[7],  // W_ih
      (const float*)d_in[8],  // W_hh
      (const float*)d_in[9],  // b_ih
      (const float*)d_in[10], // b_hh
      (const float*)d_in[11], // W_pred
      (const float*)d_in[12], // b_pred
      (float*)d_out);
}